// Round 1
// baseline (464.178 us; speedup 1.0000x reference)
//
#include <hip/hip_runtime.h>
#include <cstddef>
#include <cstdint>

// Problem constants (match reference setup_inputs()).
#define N_NODES 100000
#define N_EDGES 640000
#define EMBD    128
#define NBATCH  16384
#define CHUNK   1024
#define NCHUNK  ((N_NODES + CHUNK - 1) / CHUNK)   // 98
#define BELEMS  49152                              // 3 planes * 128 * 128 per layer

// MFMA fragment types (guide §3: bf16 16x16x32 -> short8 / float4).
typedef short bf16x8 __attribute__((ext_vector_type(8)));
typedef float f32x4  __attribute__((ext_vector_type(4)));

// ---------------------------------------------------------------------------
// Split-bf16: uint32 = bf16(x) [hi16] | bf16(x - hi) [lo16], RNE both.
// a*b via ah*bh + ah*bl + al*bh (3 MFMAs) drops only lo*lo (~2^-18 rel).
// r14: all split matrices now live as TWO ushort PLANES (H and L) so the
// GEMM stages with pure uint4 copies (no per-chunk pack/de-interleave VALU,
// which was the r13 bottleneck: VALUBusy 24% vs MfmaUtil 14%).
// ---------------------------------------------------------------------------
__device__ __forceinline__ unsigned pack_split(float x) {
    unsigned u  = __float_as_uint(x);
    unsigned hi = (u + 0x7fffu + ((u >> 16) & 1u)) & 0xffff0000u;
    float    lo = x - __uint_as_float(hi);
    unsigned ul = __float_as_uint(lo);
    unsigned lw = ((ul + 0x7fffu + ((ul >> 16) & 1u)) >> 16) & 0xffffu;
    return hi | lw;
}
__device__ __forceinline__ float bf2f(unsigned short h) {
    return __uint_as_float((unsigned)h << 16);
}

// ---------------------------------------------------------------------------
// Fused preprocess:
//  - split emb into H/L planes (thread j handles elements 2j, 2j+1)
//  - per-dst-node edge histogram
//  - dedupe head nodes into nlist (layer-2 computes only these rows)
//  - pre-pack BOTH layers' weights into tile-contiguous split planes:
//      Bp[layer][((kc*2+half)*128 + col)*16 + j]  (kc 0..11, half 0..1, j 0..15)
//    so the GEMM's B-stage is 4 coalesced uint4 loads per chunk.
// ---------------------------------------------------------------------------
__global__ __launch_bounds__(256) void pack_hist(
    const float* __restrict__ emb,
    unsigned short* __restrict__ xH, unsigned short* __restrict__ xL,
    const int* __restrict__ ei, int* __restrict__ cursor,
    const int* __restrict__ ui, const int* __restrict__ vi,
    int* __restrict__ flag, int* __restrict__ nlist, int* __restrict__ count,
    const float* __restrict__ w1rel, const float* __restrict__ w1root,
    const float* __restrict__ w2rel, const float* __restrict__ w2root,
    unsigned short* __restrict__ BpH, unsigned short* __restrict__ BpL,
    int n2, int E)
{
    const int j = blockIdx.x * 256 + threadIdx.x;
    if (j < n2) {
        const float2 v = ((const float2*)emb)[j];
        const unsigned p0 = pack_split(v.x);
        const unsigned p1 = pack_split(v.y);
        ((unsigned*)xH)[j] = (p1 & 0xffff0000u) | (p0 >> 16);
        ((unsigned*)xL)[j] = (p1 << 16) | (p0 & 0xffffu);
    }
    if (j < E) atomicAdd(&cursor[ei[E + j]], 1);
    if (j < 2 * NBATCH) {
        const int idx = (j < NBATCH) ? ui[j] : vi[j - NBATCH];
        if (atomicExch(&flag[idx], 1) == 0)
            nlist[atomicAdd(count, 1)] = idx;
    }
    if (j < 2 * BELEMS) {
        const int lay = (j >= BELEMS);
        const int q   = j - lay * BELEMS;
        const int p   = q >> 14;          // 0,1: relation planes; 2: root
        const int rem = q & 16383;
        const int k   = rem >> 7;         // 0..127 within plane
        const int c   = rem & 127;
        const float* wr = lay ? w2rel : w1rel;
        const float* wo = lay ? w2root : w1root;
        const float v = (p < 2) ? wr[(size_t)(p * 128 + k) * 128 + c]
                                : wo[(size_t)k * 128 + c];
        const unsigned ps = pack_split(v);
        const int kc   = p * 4 + (k >> 5);
        const int half = (k >> 4) & 1;
        const int jj   = k & 15;
        const size_t dst = ((size_t)(kc * 2 + half) * 128 + c) * 16 + jj;
        BpH[(size_t)lay * BELEMS + dst] = (unsigned short)(ps >> 16);
        BpL[(size_t)lay * BELEMS + dst] = (unsigned short)(ps & 0xffffu);
    }
}

// ---------------------------------------------------------------------------
// Scan phase 1: per-chunk exclusive scan (in place) + chunk total to bsum.
// ---------------------------------------------------------------------------
__global__ __launch_bounds__(256) void scan_local(
    int* __restrict__ cursor, int* __restrict__ bsum, int n)
{
    __shared__ int part[256];
    const int t    = threadIdx.x;
    const int base = blockIdx.x * CHUNK + t * 4;
    int v[4];
    int s = 0;
#pragma unroll
    for (int i = 0; i < 4; ++i) {
        const int idx = base + i;
        v[i] = (idx < n) ? cursor[idx] : 0;
        s += v[i];
    }
    part[t] = s;
    __syncthreads();
    for (int off = 1; off < 256; off <<= 1) {
        const int add = (t >= off) ? part[t - off] : 0;
        __syncthreads();
        part[t] += add;
        __syncthreads();
    }
    if (t == 255) bsum[blockIdx.x] = part[255];
    int run = (t == 0) ? 0 : part[t - 1];
#pragma unroll
    for (int i = 0; i < 4; ++i) {
        const int idx = base + i;
        if (idx < n) { cursor[idx] = run; run += v[i]; }
    }
}

// ---------------------------------------------------------------------------
// Scan phase 2 (folded): each block reduces bsum[0..blockIdx) itself and
// adds the offset to its chunk. (Validated in r11.)
// ---------------------------------------------------------------------------
__global__ __launch_bounds__(256) void scan_add(
    int* __restrict__ cursor, const int* __restrict__ bsum, int n)
{
    __shared__ int red[256];
    const int t = threadIdx.x;
    const int b = blockIdx.x;
    red[t] = (t < b && t < NCHUNK) ? bsum[t] : 0;
    __syncthreads();
    for (int off = 128; off > 0; off >>= 1) {
        if (t < off) red[t] += red[t + off];
        __syncthreads();
    }
    const int off_ = red[0];
    const int base = b * CHUNK + t * 4;
#pragma unroll
    for (int i = 0; i < 4; ++i) {
        const int idx = base + i;
        if (idx < n) cursor[idx] += off_;
    }
}

// ---------------------------------------------------------------------------
// Bucket edges into dst-sorted order. After this, cursor[n] == END of node
// n's run. Record: src (17b) | rel (1b @17) in .x, weight bits in .y.
// ---------------------------------------------------------------------------
__global__ __launch_bounds__(256) void bucket_kernel(
    const int* __restrict__ ei, const int* __restrict__ et,
    const float* __restrict__ ew, int* __restrict__ cursor,
    int2* __restrict__ srec, int E)
{
    const int e = blockIdx.x * 256 + threadIdx.x;
    if (e >= E) return;
    const int src = ei[e];
    const int dst = ei[E + e];
    const int r   = et[e];
    const int pos = atomicAdd(&cursor[dst], 1);
    srec[pos] = make_int2(src | (r << 17), __float_as_int(ew[e]));
}

// ---------------------------------------------------------------------------
// accum core: one wave accumulates node `wid`'s edges (bf16-hi gathers,
// 4 B/lane/edge — r12-proven) and stores both relations as H/L planes.
// ---------------------------------------------------------------------------
__device__ __forceinline__ void accum_node(
    const unsigned short* __restrict__ xh, const int2* __restrict__ srec,
    const int* __restrict__ cursor,
    unsigned short* __restrict__ AH, unsigned short* __restrict__ AL,
    int wid, int lane, int N)
{
    const int s = (wid == 0) ? 0 : cursor[wid - 1];
    const int e = cursor[wid];

    float ax = 0.f, ay = 0.f, bx = 0.f, by = 0.f;
    int i = s;
    for (; i + 3 < e; i += 4) {
        const int2 r0 = srec[i];
        const int2 r1 = srec[i + 1];
        const int2 r2 = srec[i + 2];
        const int2 r3 = srec[i + 3];
        const unsigned g0 = ((const unsigned*)(xh + (size_t)(r0.x & 0x1FFFF) * EMBD))[lane];
        const unsigned g1 = ((const unsigned*)(xh + (size_t)(r1.x & 0x1FFFF) * EMBD))[lane];
        const unsigned g2 = ((const unsigned*)(xh + (size_t)(r2.x & 0x1FFFF) * EMBD))[lane];
        const unsigned g3 = ((const unsigned*)(xh + (size_t)(r3.x & 0x1FFFF) * EMBD))[lane];
        const float w0 = __int_as_float(r0.y);
        const float w1 = __int_as_float(r1.y);
        const float w2 = __int_as_float(r2.y);
        const float w3 = __int_as_float(r3.y);
        {
            const float vx = bf2f((unsigned short)(g0 & 0xffffu));
            const float vy = bf2f((unsigned short)(g0 >> 16));
            if (r0.x & (1 << 17)) { bx += vx * w0; by += vy * w0; }
            else                  { ax += vx * w0; ay += vy * w0; }
        }
        {
            const float vx = bf2f((unsigned short)(g1 & 0xffffu));
            const float vy = bf2f((unsigned short)(g1 >> 16));
            if (r1.x & (1 << 17)) { bx += vx * w1; by += vy * w1; }
            else                  { ax += vx * w1; ay += vy * w1; }
        }
        {
            const float vx = bf2f((unsigned short)(g2 & 0xffffu));
            const float vy = bf2f((unsigned short)(g2 >> 16));
            if (r2.x & (1 << 17)) { bx += vx * w2; by += vy * w2; }
            else                  { ax += vx * w2; ay += vy * w2; }
        }
        {
            const float vx = bf2f((unsigned short)(g3 & 0xffffu));
            const float vy = bf2f((unsigned short)(g3 >> 16));
            if (r3.x & (1 << 17)) { bx += vx * w3; by += vy * w3; }
            else                  { ax += vx * w3; ay += vy * w3; }
        }
    }
    for (; i < e; ++i) {
        const int2 r0 = srec[i];
        const unsigned g0 = ((const unsigned*)(xh + (size_t)(r0.x & 0x1FFFF) * EMBD))[lane];
        const float w0 = __int_as_float(r0.y);
        const float vx = bf2f((unsigned short)(g0 & 0xffffu));
        const float vy = bf2f((unsigned short)(g0 >> 16));
        if (r0.x & (1 << 17)) { bx += vx * w0; by += vy * w0; }
        else                  { ax += vx * w0; ay += vy * w0; }
    }
    const unsigned pax = pack_split(ax), pay = pack_split(ay);
    const unsigned pbx = pack_split(bx), pby = pack_split(by);
    ((unsigned*)(AH + (size_t)wid * EMBD))[lane]       = (pay & 0xffff0000u) | (pax >> 16);
    ((unsigned*)(AL + (size_t)wid * EMBD))[lane]       = (pay << 16) | (pax & 0xffffu);
    ((unsigned*)(AH + ((size_t)N + wid) * EMBD))[lane] = (pby & 0xffff0000u) | (pbx >> 16);
    ((unsigned*)(AL + ((size_t)N + wid) * EMBD))[lane] = (pby << 16) | (pbx & 0xffffu);
}

// All nodes (layer 1).
__global__ __launch_bounds__(256) void accum_csr(
    const unsigned short* __restrict__ xh, const int2* __restrict__ srec,
    const int* __restrict__ cursor,
    unsigned short* __restrict__ AH, unsigned short* __restrict__ AL, int N)
{
    const int wid = blockIdx.x * 4 + (threadIdx.x >> 6);
    accum_node(xh, srec, cursor, AH, AL, wid, threadIdx.x & 63, N);
}

// Listed nodes only (layer 2 — head reads only ~28k of 100k rows).
__global__ __launch_bounds__(256) void accum_csr_list(
    const unsigned short* __restrict__ xh, const int2* __restrict__ srec,
    const int* __restrict__ cursor, const int* __restrict__ nlist,
    const int* __restrict__ count,
    unsigned short* __restrict__ AH, unsigned short* __restrict__ AL, int N)
{
    const int wi = blockIdx.x * 4 + (threadIdx.x >> 6);
    if (wi >= *count) return;   // per-wave exit; no barriers in this kernel
    accum_node(xh, srec, cursor, AH, AL, nlist[wi], threadIdx.x & 63, N);
}

// ---------------------------------------------------------------------------
// Split-bf16 MFMA GEMM, r14 plane form: A and B arrive pre-split as H/L
// ushort planes, so staging is pure uint4 global->reg->LDS copies, both
// prefetched one chunk ahead. No pack_split / de-interleave inside the loop
// (r13's VALU bottleneck: 16 pack_split + 8-step shuffle per chunk).
// Fragment layouts (m89/m120 verified): A[m=lane&15][k=quad*8+j];
// C/D col=lane&15, row=quad*4+reg. LDS rows 80 B so b128 reads are ~2-way
// bank aliased (free, m136).
// Output is written as H/L planes too (outH/outL), row-for-row aliasable
// with S2H/S2L: each block reads only its own (unique, listed) rows before
// writing the same rows.
// ---------------------------------------------------------------------------
__global__ __launch_bounds__(256) void gemm_mfma(
    const unsigned short* __restrict__ S0H, const unsigned short* __restrict__ S0L,
    const unsigned short* __restrict__ S1H, const unsigned short* __restrict__ S1L,
    const unsigned short* __restrict__ S2H, const unsigned short* __restrict__ S2L,
    const unsigned short* __restrict__ BpH, const unsigned short* __restrict__ BpL,
    const float* __restrict__ bias, const float* __restrict__ lng,
    const float* __restrict__ lnb,
    unsigned short* __restrict__ outH, unsigned short* __restrict__ outL,
    const int* __restrict__ rowlist, const int* __restrict__ rowcnt,
    int M, int do_ln)
{
    __shared__ unsigned short AsH[128 * 40], AsL[128 * 40];   // 10 KB each
    __shared__ unsigned short BsH[128 * 40], BsL[128 * 40];
    __shared__ float lnbuf[2][128][2];
    __shared__ int rows[128];

    const int t    = threadIdx.x;
    const int wave = t >> 6;
    const int lane = t & 63;
    const int q    = lane >> 4;
    const int n    = lane & 15;
    const int wrow = wave & 1;
    const int wcol = wave >> 1;
    const int m0   = blockIdx.x * 128;

    const int cnt = rowcnt ? *rowcnt : M;
    if (m0 >= cnt) return;                      // uniform across block
    if (t < 128) {
        const int rr = m0 + t;
        rows[t] = (rr < cnt) ? (rowlist ? rowlist[rr] : rr) : -1;
    }
    __syncthreads();

    const int arow  = t >> 1;        // 0..127
    const int ahalf = t & 1;         // which 16-elem half of the 32-k chunk
    const int bcol  = t & 127;
    const int bkh   = t >> 7;        // which 16-k half

    f32x4 acc[4][4];
#pragma unroll
    for (int rt = 0; rt < 4; ++rt)
#pragma unroll
        for (int ct = 0; ct < 4; ++ct)
            acc[rt][ct] = (f32x4){0.f, 0.f, 0.f, 0.f};

    uint4 au0, au1, au2, au3;        // A prefetch (H then L), 16 VGPRs
    uint4 bu0, bu1, bu2, bu3;        // B prefetch (H then L), 16 VGPRs
    auto loadA = [&](int kc) {
        const unsigned short* SH = (kc < 4) ? S0H : (kc < 8) ? S1H : S2H;
        const unsigned short* SL = (kc < 4) ? S0L : (kc < 8) ? S1L : S2L;
        const int node = rows[arow];
        if (node >= 0) {
            const size_t off = (size_t)node * EMBD + (kc & 3) * 32 + ahalf * 16;
            au0 = *(const uint4*)(SH + off);
            au1 = *(const uint4*)(SH + off + 8);
            au2 = *(const uint4*)(SL + off);
            au3 = *(const uint4*)(SL + off + 8);
        } else {
            au0 = au1 = au2 = au3 = make_uint4(0u, 0u, 0u, 0u);
        }
    };
    auto loadB = [&](int kc) {
        const size_t off = ((size_t)(kc * 2 + bkh) * 128 + bcol) * 16;
        bu0 = *(const uint4*)(BpH + off);
        bu1 = *(const uint4*)(BpH + off + 8);
        bu2 = *(const uint4*)(BpL + off);
        bu3 = *(const uint4*)(BpL + off + 8);
    };

    loadA(0);
    loadB(0);

    for (int kc = 0; kc < 12; ++kc) {
        __syncthreads();   // previous chunk's frag reads done before overwrite

        // ---- stage prefetched regs -> LDS (pure copies) ----
        {
            uint4* pH = (uint4*)(AsH + arow * 40 + ahalf * 16);
            uint4* pL = (uint4*)(AsL + arow * 40 + ahalf * 16);
            pH[0] = au0; pH[1] = au1;
            pL[0] = au2; pL[1] = au3;
            uint4* qH = (uint4*)(BsH + bcol * 40 + bkh * 16);
            uint4* qL = (uint4*)(BsL + bcol * 40 + bkh * 16);
            qH[0] = bu0; qH[1] = bu1;
            qL[0] = bu2; qL[1] = bu3;
        }

        if (kc < 11) { loadA(kc + 1); loadB(kc + 1); }  // in flight under MFMAs
        __syncthreads();

        // ---- fragments + MFMA ----
        bf16x8 ah[4], al[4];
#pragma unroll
        for (int rt = 0; rt < 4; ++rt) {
            const int r = wrow * 64 + rt * 16 + n;
            ah[rt] = *(const bf16x8*)&AsH[r * 40 + q * 8];
            al[rt] = *(const bf16x8*)&AsL[r * 40 + q * 8];
        }
#pragma unroll
        for (int ct = 0; ct < 4; ++ct) {
            const int c = wcol * 64 + ct * 16 + n;
            const bf16x8 bh = *(const bf16x8*)&BsH[c * 40 + q * 8];
            const bf16x8 bl = *(const bf16x8*)&BsL[c * 40 + q * 8];
#pragma unroll
            for (int rt = 0; rt < 4; ++rt) {
                acc[rt][ct] = __builtin_amdgcn_mfma_f32_16x16x32_bf16(ah[rt], bh, acc[rt][ct], 0, 0, 0);
                acc[rt][ct] = __builtin_amdgcn_mfma_f32_16x16x32_bf16(ah[rt], bl, acc[rt][ct], 0, 0, 0);
                acc[rt][ct] = __builtin_amdgcn_mfma_f32_16x16x32_bf16(al[rt], bh, acc[rt][ct], 0, 0, 0);
            }
        }
    }

    // ---- epilogue ----
    float bb[4], gg[4], tb[4];
#pragma unroll
    for (int ct = 0; ct < 4; ++ct) {
        const int c = wcol * 64 + ct * 16 + n;
        bb[ct] = bias[c];
        gg[ct] = do_ln ? lng[c] : 0.f;
        tb[ct] = do_ln ? lnb[c] : 0.f;
    }

    if (do_ln) {
#pragma unroll
        for (int rt = 0; rt < 4; ++rt)
#pragma unroll
            for (int r = 0; r < 4; ++r) {
                float s = 0.f, sq = 0.f;
#pragma unroll
                for (int ct = 0; ct < 4; ++ct) {
                    float v = acc[rt][ct][r] + bb[ct];
                    v = fmaxf(v, 0.f);
                    acc[rt][ct][r] = v;
                    s += v; sq += v * v;
                }
#pragma unroll
                for (int off = 1; off < 16; off <<= 1) {
                    s  += __shfl_xor(s,  off, 64);
                    sq += __shfl_xor(sq, off, 64);
                }
                if (n == 0) {
                    const int row = wrow * 64 + rt * 16 + q * 4 + r;
                    lnbuf[wcol][row][0] = s;
                    lnbuf[wcol][row][1] = sq;
                }
            }
        __syncthreads();
#pragma unroll
        for (int rt = 0; rt < 4; ++rt)
#pragma unroll
            for (int r = 0; r < 4; ++r) {
                const int row  = wrow * 64 + rt * 16 + q * 4 + r;
                const int node = rows[row];
                const float s    = lnbuf[0][row][0] + lnbuf[1][row][0];
                const float sq   = lnbuf[0][row][1] + lnbuf[1][row][1];
                const float mu   = s * (1.0f / 128.0f);
                const float var  = sq * (1.0f / 128.0f) - mu * mu;
                const float rstd = rsqrtf(var + 1e-5f);
                if (node >= 0) {
#pragma unroll
                    for (int ct = 0; ct < 4; ++ct) {
                        const int c = wcol * 64 + ct * 16 + n;
                        const float v = (acc[rt][ct][r] - mu) * rstd * gg[ct] + tb[ct];
                        const unsigned p = pack_split(v);
                        outH[(size_t)node * EMBD + c] = (unsigned short)(p >> 16);
                        outL[(size_t)node * EMBD + c] = (unsigned short)(p & 0xffffu);
                    }
                }
            }
    } else {
#pragma unroll
        for (int rt = 0; rt < 4; ++rt)
#pragma unroll
            for (int r = 0; r < 4; ++r) {
                const int node = rows[wrow * 64 + rt * 16 + q * 4 + r];
                if (node >= 0) {
#pragma unroll
                    for (int ct = 0; ct < 4; ++ct) {
                        const int c = wcol * 64 + ct * 16 + n;
                        const unsigned p = pack_split(acc[rt][ct][r] + bb[ct]);
                        outH[(size_t)node * EMBD + c] = (unsigned short)(p >> 16);
                        outL[(size_t)node * EMBD + c] = (unsigned short)(p & 0xffffu);
                    }
                }
            }
    }
}

// ---------------------------------------------------------------------------
// Fused head: gather u/v (split-pair reconstruct), l2 norms, GMF, MLP
// 256->128->64->32, out proj, sigmoid. 16 batch rows per 256-thread block.
// ---------------------------------------------------------------------------
__global__ __launch_bounds__(256) void head_kernel(
    const unsigned short* __restrict__ x2H, const unsigned short* __restrict__ x2L,
    const int* __restrict__ ui, const int* __restrict__ vi,
    const float* __restrict__ mw0, const float* __restrict__ mb0,
    const float* __restrict__ mw1, const float* __restrict__ mb1,
    const float* __restrict__ mw2, const float* __restrict__ mb2,
    const float* __restrict__ ow, const float* __restrict__ ob,
    float* __restrict__ out, int B)
{
    __shared__ float h0[16][256];
    __shared__ float h1[16][128];
    __shared__ float h2[16][64];
    __shared__ float h3[16][32];
    __shared__ float ps_u[16][16], ps_v[16][16];
    __shared__ float inv_nunv[16];
    __shared__ float pg[16][16], ph[16][16];

    const int t   = threadIdx.x;
    const int bb0 = blockIdx.x * 16;

    for (int r = 0; r < 16; ++r) {
        const int b   = bb0 + r;
        const int idx = (t < 128) ? ui[b] : vi[b];
        const int c   = t & 127;
        const size_t o = (size_t)idx * EMBD + c;
        h0[r][t] = bf2f(x2H[o]) + bf2f(x2L[o]);
    }
    __syncthreads();

    {
        const int row = t >> 4, sub = t & 15;
        float su = 0.f, sv = 0.f;
#pragma unroll
        for (int k = 0; k < 8; ++k) {
            const float a = h0[row][sub + 16 * k];       su += a * a;
            const float b = h0[row][128 + sub + 16 * k]; sv += b * b;
        }
        ps_u[row][sub] = su; ps_v[row][sub] = sv;
    }
    __syncthreads();
    if (t < 16) {
        float su = 0.f, sv = 0.f;
#pragma unroll
        for (int k = 0; k < 16; ++k) { su += ps_u[t][k]; sv += ps_v[t][k]; }
        const float nu = fmaxf(sqrtf(su), 1e-12f);
        const float nv = fmaxf(sqrtf(sv), 1e-12f);
        inv_nunv[t] = 1.0f / (nu * nv);
    }
    __syncthreads();

    {
        const int c = t & 127, rr = t >> 7;
        float acc[8];
#pragma unroll
        for (int j = 0; j < 8; ++j) acc[j] = 0.f;
        for (int i = 0; i < 256; i += 4) {
            const float w0 = mw0[(i + 0) * 128 + c];
            const float w1 = mw0[(i + 1) * 128 + c];
            const float w2 = mw0[(i + 2) * 128 + c];
            const float w3 = mw0[(i + 3) * 128 + c];
#pragma unroll
            for (int j = 0; j < 8; ++j) {
                const float4 a = *(const float4*)&h0[rr * 8 + j][i];
                acc[j] += a.x * w0 + a.y * w1 + a.z * w2 + a.w * w3;
            }
        }
        const float bv = mb0[c];
#pragma unroll
        for (int j = 0; j < 8; ++j) h1[rr * 8 + j][c] = fmaxf(acc[j] + bv, 0.f);
    }
    __syncthreads();

    {
        const int c = t & 63, g = t >> 6;
        float acc[4] = {0.f, 0.f, 0.f, 0.f};
        for (int i = 0; i < 128; i += 4) {
            const float w0 = mw1[(i + 0) * 64 + c];
            const float w1 = mw1[(i + 1) * 64 + c];
            const float w2 = mw1[(i + 2) * 64 + c];
            const float w3 = mw1[(i + 3) * 64 + c];
#pragma unroll
            for (int j = 0; j < 4; ++j) {
                const float4 a = *(const float4*)&h1[g * 4 + j][i];
                acc[j] += a.x * w0 + a.y * w1 + a.z * w2 + a.w * w3;
            }
        }
        const float bv = mb1[c];
#pragma unroll
        for (int j = 0; j < 4; ++j) h2[g * 4 + j][c] = fmaxf(acc[j] + bv, 0.f);
    }
    __syncthreads();

    {
        const int c = t & 31, g = t >> 5;
        float acc[2] = {0.f, 0.f};
        for (int i = 0; i < 64; i += 4) {
            const float w0 = mw2[(i + 0) * 32 + c];
            const float w1 = mw2[(i + 1) * 32 + c];
            const float w2 = mw2[(i + 2) * 32 + c];
            const float w3 = mw2[(i + 3) * 32 + c];
#pragma unroll
            for (int j = 0; j < 2; ++j) {
                const float4 a = *(const float4*)&h2[g * 2 + j][i];
                acc[j] += a.x * w0 + a.y * w1 + a.z * w2 + a.w * w3;
            }
        }
        const float bv = mb2[c];
#pragma unroll
        for (int j = 0; j < 2; ++j) h3[g * 2 + j][c] = fmaxf(acc[j] + bv, 0.f);
    }
    __syncthreads();

    {
        const int row = t >> 4, sub = t & 15;
        float pgv = 0.f;
#pragma unroll
        for (int k = 0; k < 8; ++k) {
            const int c = sub + 16 * k;
            pgv += h0[row][c] * h0[row][128 + c] * ow[c];
        }
        const float phv = h3[row][sub]      * ow[128 + sub]
                        + h3[row][sub + 16] * ow[144 + sub];
        pg[row][sub] = pgv; ph[row][sub] = phv;
    }
    __syncthreads();
    if (t < 16) {
        float sg = 0.f, sh = 0.f;
#pragma unroll
        for (int k = 0; k < 16; ++k) { sg += pg[t][k]; sh += ph[t][k]; }
        const float z = sg * inv_nunv[t] + sh + ob[0];
        out[bb0 + t] = 1.0f / (1.0f + expf(-z));
    }
}

// ---------------------------------------------------------------------------
// Launch. ws layout (~159.3 MB; previous session proved ws >= 185.3 MB):
//   aggH[2][N][128] ush  51.2 MB  (aggregate hi planes, both relations)
//   aggL[2][N][128] ush  51.2 MB
//   xH[N][128]      ush  25.6 MB  (emb hi -> x1 hi -> x2 hi, row-aliased)
//   xL[N][128]      ush  25.6 MB  (emb lo -> x1 lo -> x2 lo, row-aliased)
//   srec[E] int2          5.12 MB
//   BpH[2][49152]   ush   0.20 MB (pre-packed B hi, both layers)
//   BpL[2][49152]   ush   0.20 MB
//   cursor[N], flag[N], count[1]   (one contiguous memset)
//   bsum[NCHUNK], nlist[2*NBATCH]
// Row-alias safety: every gemm block reads only its own UNIQUE rows of all
// S planes, and writes the same rows strictly after its reads.
// ---------------------------------------------------------------------------
extern "C" void kernel_launch(void* const* d_in, const int* in_sizes, int n_in,
                              void* d_out, int out_size, void* d_ws, size_t ws_size,
                              hipStream_t stream)
{
    const int*   ui      = (const int*)d_in[0];
    const int*   vi      = (const int*)d_in[1];
    const int*   ei      = (const int*)d_in[2];
    const int*   et      = (const int*)d_in[3];
    const float* ew      = (const float*)d_in[4];
    const float* emb     = (const float*)d_in[5];
    const float* w1_rel  = (const float*)d_in[6];
    const float* w1_root = (const float*)d_in[7];
    const float* b1      = (const float*)d_in[8];
    const float* ln_g    = (const float*)d_in[9];
    const float* ln_b    = (const float*)d_in[10];
    const float* w2_rel  = (const float*)d_in[11];
    const float* w2_root = (const float*)d_in[12];
    const float* b2      = (const float*)d_in[13];
    const float* mw0     = (const float*)d_in[14];
    const float* mb0     = (const float*)d_in[15];
    const float* mw1     = (const float*)d_in[16];
    const float* mb1     = (const float*)d_in[17];
    const float* mw2     = (const float*)d_in[18];
    const float* mb2     = (const float*)d_in[19];
    const float* ow      = (const float*)d_in[20];
    const float* ob      = (const float*)d_in[21];
    float* out = (float*)d_out;

    const int N = N_NODES, E = N_EDGES, B = NBATCH;

    unsigned short* aggH = (unsigned short*)d_ws;                    // [2][N][128]
    unsigned short* aggL = aggH + (size_t)2 * N * EMBD;
    unsigned short* xH   = aggL + (size_t)2 * N * EMBD;              // [N][128]
    unsigned short* xL   = xH + (size_t)N * EMBD;
    int2*           srec = (int2*)(xL + (size_t)N * EMBD);
    unsigned short* BpH  = (unsigned short*)(srec + E);              // [2][BELEMS]
    unsigned short* BpL  = BpH + (size_t)2 * BELEMS;
    int*            cursor = (int*)(BpL + (size_t)2 * BELEMS);
    int*            flag   = cursor + N;
    int*            count  = flag + N;
    int*            bsum   = count + 1;
    int*            nlist  = bsum + NCHUNK;

    // ---- Preprocess: split emb, pre-pack B, histogram, node dedupe ----
    hipMemsetAsync(cursor, 0, (size_t)(2 * N + 1) * sizeof(int), stream);
    pack_hist<<<(N * EMBD / 2 + 255) / 256, 256, 0, stream>>>(
        emb, xH, xL, ei, cursor, ui, vi, flag, nlist, count,
        w1_rel, w1_root, w2_rel, w2_root, BpH, BpL,
        N * EMBD / 2, E);

    // ---- Sort edges by dst node (once; shared by both layers) ----
    scan_local<<<NCHUNK, 256, 0, stream>>>(cursor, bsum, N);
    scan_add<<<NCHUNK, 256, 0, stream>>>(cursor, bsum, N);
    bucket_kernel<<<(E + 255) / 256, 256, 0, stream>>>(ei, et, ew, cursor, srec, E);

    // ---- Layer 1: full accum -> full GEMM + relu + LN (H/L planes out) ----
    accum_csr<<<N / 4, 256, 0, stream>>>(xH, srec, cursor, aggH, aggL, N);
    gemm_mfma<<<(N + 127) / 128, 256, 0, stream>>>(
        aggH, aggL, aggH + (size_t)N * EMBD, aggL + (size_t)N * EMBD, xH, xL,
        BpH, BpL, b1, ln_g, ln_b, xH, xL,
        nullptr, nullptr, N, 1);

    // ---- Layer 2: LIST-restricted accum + GEMM (head rows only) ----
    accum_csr_list<<<(2 * NBATCH) / 4, 256, 0, stream>>>(
        xH, srec, cursor, nlist, count, aggH, aggL, N);
    gemm_mfma<<<(2 * NBATCH + 127) / 128, 256, 0, stream>>>(
        aggH, aggL, aggH + (size_t)N * EMBD, aggL + (size_t)N * EMBD, xH, xL,
        BpH + BELEMS, BpL + BELEMS, b2, nullptr, nullptr, xH, xL,
        nlist, count, N, 0);

    // ---- Head ----
    head_kernel<<<B / 16, 256, 0, stream>>>(
        xH, xL, ui, vi, mw0, mb0, mw1, mb1, mw2, mb2, ow, ob, out, B);
}